// Round 8
// baseline (88.263 us; speedup 1.0000x reference)
//
#include <hip/hip_runtime.h>
#include <hip/hip_bf16.h>

typedef unsigned short u16;
typedef unsigned int u32;
typedef __attribute__((ext_vector_type(8))) short short8;
typedef __attribute__((ext_vector_type(4))) float f32x4;

#define KDIM 2048
#define NP 1024

__device__ __forceinline__ float b2f(u16 u){
  union{u32 i; float f;} v; v.i = ((u32)u)<<16; return v.f;
}
__device__ __forceinline__ u16 f2b(float f){
  u32 x = __float_as_uint(f);
  return (u16)((x + 0x7fffu + ((x>>16)&1u)) >> 16);
}

__device__ __forceinline__ void gload16(const void* g, u16* l){
  __builtin_amdgcn_global_load_lds((const __attribute__((address_space(1))) u32*)g,
                                   (__attribute__((address_space(3))) u32*)l, 16, 0, 0);
}

// 8 f32 -> short8 of bf16 (RNE) via v_cvt_pk_bf16_f32 (no builtin on gfx950)
__device__ __forceinline__ short8 cvt8(float4 a, float4 c){
  union { short8 s; u32 w[4]; } u;
  asm("v_cvt_pk_bf16_f32 %0, %1, %2" : "=v"(u.w[0]) : "v"(a.x), "v"(a.y));
  asm("v_cvt_pk_bf16_f32 %0, %1, %2" : "=v"(u.w[1]) : "v"(a.z), "v"(a.w));
  asm("v_cvt_pk_bf16_f32 %0, %1, %2" : "=v"(u.w[2]) : "v"(c.x), "v"(c.y));
  asm("v_cvt_pk_bf16_f32 %0, %1, %2" : "=v"(u.w[3]) : "v"(c.z), "v"(c.w));
  return u.s;
}

// ---- K0: W -> bf16 padded (1024x2048) + phi -> phiT bf16 (32x1024) ----
__global__ __launch_bounds__(256) void k_prep(const float* __restrict__ W, const float* __restrict__ phi,
                                              u16* __restrict__ Wb, u16* __restrict__ phiT){
  int bid = blockIdx.x;
  if (bid < 1024){
    int i = bid*256 + threadIdx.x;
    int e = i*8; int row = e >> 11;
    u32 o0=0,o1=0,o2=0,o3=0;
    if (row < 1023){
      const float4* s = (const float4*)(W + e);
      float4 a = s[0], c = s[1];
      o0 = (u32)f2b(a.x) | ((u32)f2b(a.y)<<16);
      o1 = (u32)f2b(a.z) | ((u32)f2b(a.w)<<16);
      o2 = (u32)f2b(c.x) | ((u32)f2b(c.y)<<16);
      o3 = (u32)f2b(c.z) | ((u32)f2b(c.w)<<16);
    }
    *(uint4*)(Wb + e) = make_uint4(o0,o1,o2,o3);
  } else {
    int i = (bid-1024)*256 + threadIdx.x;
    int d = i >> 10, leaf = i & 1023;
    float v = (d < 24) ? phi[leaf*24 + d] : 0.f;
    phiT[i] = f2b(v);
  }
}

// ---- K1: probs = sigmoid(xs @ Wb^T + b), A staged as f32 via global_load_lds ----
// BM=128 BN=256 BK=64, 512 thr (8 waves 2Mx4N, 64x64/wave -- R2-proven per-wave
// geometry), dbuf LDS 128KB (A f32 32KB + B bf16 32KB per buf), 2 phases/tile,
// counted vmcnt(4), XOR swizzle, XCD block swizzle. A frags: f32x4 pair + cvt_pk.
__global__ __launch_bounds__(512, 2) void k_gemm_sig(const float* __restrict__ xs, const u16* __restrict__ Wb,
                                                     const float* __restrict__ b, u16* __restrict__ probs){
  extern __shared__ u16 smem[];                   // [buf][ A:16384 u16 | B:16384 u16 ], 2 bufs
  const int t = threadIdx.x;
  const int l = t & 63;
  const int w = t >> 6;
  const int wm = w >> 2, wn = w & 3;              // 2M x 4N wave grid, 64x64 each
  const int bid = (int)blockIdx.x;
  const int wg = (bid & 7) * 32 + (bid >> 3);     // XCD-chunked, bijective (256%8==0)
  const int rowB = (wg >> 2) * 128;
  const int colB = (wg & 3) * 256;

  // A staging (f32, 16B = 4 f32 chunks; 16 chunks/row): pass p covers rows p*32..+31
  // linear dest chunk loc = p*512+t -> row = p*32+(t>>4), src chunk = (t&15)^((t>>4)&7)
  const float* gAf = xs + (size_t)(rowB + (t>>4)) * KDIM + ((t&15) ^ ((t>>4)&7)) * 4;
  const int dA = t*8;                             // u16 units; + p*4096
  // B staging (bf16, 8 chunks/row): loc = p*512+t -> row = p*64+(t>>3), chunk=(t&7)^((t>>3)&7)
  const u16* gBb = Wb + (size_t)(colB + (t>>3)) * KDIM + ((t&7) ^ ((t>>3)&7)) * 8;
  const int dB = 16384 + t*8;

  // fragment read offsets
  const int r15 = l & 15, q = l >> 4, b7 = l & 7;
  const int xa0 = ((2*q    ) ^ b7) * 8;           // A ks0 chunk (u16 off); pair at ^8
  const int xa1 = ((2*q + 8) ^ b7) * 8;           // A ks1
  const int xb0 = ((q    ) ^ b7) * 8;             // B ks0 slot
  const int xb1 = ((4 + q) ^ b7) * 8;             // B ks1
  int aOff[4], bOff[4];
  #pragma unroll
  for (int m=0;m<4;m++) aOff[m] = (wm*64 + m*16 + r15) * 128;   // f32 row = 256B = 128 u16
  #pragma unroll
  for (int n=0;n<4;n++) bOff[n] = 16384 + (wn*64 + n*16 + r15) * 64;

  f32x4 acc[4][4] = {};

#define SA(buf, ko) do{ \
    gload16(gAf + (size_t)0*32*KDIM + (ko), (buf) + 0*4096 + dA); \
    gload16(gAf + (size_t)1*32*KDIM + (ko), (buf) + 1*4096 + dA); \
    gload16(gAf + (size_t)2*32*KDIM + (ko), (buf) + 2*4096 + dA); \
    gload16(gAf + (size_t)3*32*KDIM + (ko), (buf) + 3*4096 + dA); }while(0)
#define SB(buf, ko) do{ \
    gload16(gBb + (size_t)0*64*KDIM + (ko), (buf) + 0*4096 + dB); \
    gload16(gBb + (size_t)1*64*KDIM + (ko), (buf) + 1*4096 + dB); \
    gload16(gBb + (size_t)2*64*KDIM + (ko), (buf) + 2*4096 + dB); \
    gload16(gBb + (size_t)3*64*KDIM + (ko), (buf) + 3*4096 + dB); }while(0)

  u16 *bc = smem, *bn = smem + 32768;

  SA(bc, 0); SB(bc, 0);                           // prologue: tile 0 (8 loads)

  for (int tk = 0; tk < 31; ++tk){
    const int ko = (tk + 1) * 64;
    SA(bn, ko);                                   // 4 A-loads of t+1 in flight
    asm volatile("s_waitcnt vmcnt(4)" ::: "memory");  // tile t fully landed
    __builtin_amdgcn_s_barrier();
    asm volatile("" ::: "memory");
    {                                             // phase 0: ks0
      short8 af[4], bf[4];
      #pragma unroll
      for (int m=0;m<4;m++){
        float4 f0 = *(const float4*)(bc + aOff[m] + xa0);
        float4 f1 = *(const float4*)(bc + aOff[m] + (xa0 ^ 8));
        af[m] = cvt8(f0, f1);
      }
      #pragma unroll
      for (int n=0;n<4;n++) bf[n] = *(const short8*)(bc + bOff[n] + xb0);
      __builtin_amdgcn_s_setprio(1);
      #pragma unroll
      for (int m=0;m<4;m++){
        #pragma unroll
        for (int n=0;n<4;n++) acc[m][n] = __builtin_amdgcn_mfma_f32_16x16x32_bf16(af[m], bf[n], acc[m][n], 0,0,0);
      }
      __builtin_amdgcn_s_setprio(0);
    }
    SB(bn, ko);                                   // remaining 4 loads of t+1
    {                                             // phase 1: ks1
      short8 af[4], bf[4];
      #pragma unroll
      for (int m=0;m<4;m++){
        float4 f0 = *(const float4*)(bc + aOff[m] + xa1);
        float4 f1 = *(const float4*)(bc + aOff[m] + (xa1 ^ 8));
        af[m] = cvt8(f0, f1);
      }
      #pragma unroll
      for (int n=0;n<4;n++) bf[n] = *(const short8*)(bc + bOff[n] + xb1);
      __builtin_amdgcn_s_setprio(1);
      #pragma unroll
      for (int m=0;m<4;m++){
        #pragma unroll
        for (int n=0;n<4;n++) acc[m][n] = __builtin_amdgcn_mfma_f32_16x16x32_bf16(af[m], bf[n], acc[m][n], 0,0,0);
      }
      __builtin_amdgcn_s_setprio(0);
    }
    __builtin_amdgcn_s_barrier();                 // reads of bc done; t+1 writes -> bn safe
    asm volatile("" ::: "memory");
    u16* tmp = bc; bc = bn; bn = tmp;
  }
  {                                               // tail: tile 31
    asm volatile("s_waitcnt vmcnt(0)" ::: "memory");
    __builtin_amdgcn_s_barrier();
    asm volatile("" ::: "memory");
    short8 af[4], bf[4];
    #pragma unroll
    for (int m=0;m<4;m++){
      float4 f0 = *(const float4*)(bc + aOff[m] + xa0);
      float4 f1 = *(const float4*)(bc + aOff[m] + (xa0 ^ 8));
      af[m] = cvt8(f0, f1);
    }
    #pragma unroll
    for (int n=0;n<4;n++) bf[n] = *(const short8*)(bc + bOff[n] + xb0);
    #pragma unroll
    for (int m=0;m<4;m++){
      #pragma unroll
      for (int n=0;n<4;n++) acc[m][n] = __builtin_amdgcn_mfma_f32_16x16x32_bf16(af[m], bf[n], acc[m][n], 0,0,0);
    }
    #pragma unroll
    for (int m=0;m<4;m++){
      float4 f0 = *(const float4*)(bc + aOff[m] + xa1);
      float4 f1 = *(const float4*)(bc + aOff[m] + (xa1 ^ 8));
      af[m] = cvt8(f0, f1);
    }
    #pragma unroll
    for (int n=0;n<4;n++) bf[n] = *(const short8*)(bc + bOff[n] + xb1);
    #pragma unroll
    for (int m=0;m<4;m++){
      #pragma unroll
      for (int n=0;n<4;n++) acc[m][n] = __builtin_amdgcn_mfma_f32_16x16x32_bf16(af[m], bf[n], acc[m][n], 0,0,0);
    }
  }
#undef SA
#undef SB

  #pragma unroll
  for (int n=0;n<4;n++){
    int col = colB + wn*64 + n*16 + r15;
    float bb = (col < 1023) ? b[col] : 0.f;
    #pragma unroll
    for (int m=0;m<4;m++){
      #pragma unroll
      for (int r=0;r<4;r++){
        int row = rowB + wm*64 + m*16 + q*4 + r;  // measured C/D layout
        float x = acc[m][n][r] + bb;
        float p = 1.f / (1.f + __expf(-x));
        probs[(size_t)row*NP + col] = f2b(p);
      }
    }
  }
}

// ---- K2: fused leaf products + pp@phi (LDS-staged pp, MFMA epilogue) ----
__global__ __launch_bounds__(128) void k_ppout(const u16* __restrict__ probs, const u16* __restrict__ phiT,
                                               float* __restrict__ out){
  extern __shared__ u16 ppL[];                    // 2 waves * 16 rows * 1024 = 64KB
  const int t = threadIdx.x;
  const int l = t & 63;
  const int w = t >> 6;
  u16* pl = ppL + w*16384;
  const int row0 = blockIdx.x*32 + w*16;

  for (int r=0; r<16; ++r){
    const u16* pr = probs + (size_t)(row0 + r)*NP;
    float prefix = 1.f;
    #pragma unroll
    for (int k=0;k<6;k++){
      int i = l >> (6-k);
      int bit = (l >> (5-k)) & 1;
      float p = b2f(pr[(1<<k)-1 + i]);
      prefix *= bit ? p : (1.f - p);
    }
    float p6 = b2f(pr[63 + l]);
    float p7[2], p8[4], p9[8];
    #pragma unroll
    for (int c=0;c<2;c++) p7[c] = b2f(pr[127 + 2*l + c]);
    #pragma unroll
    for (int c=0;c<4;c++) p8[c] = b2f(pr[255 + 4*l + c]);
    #pragma unroll
    for (int c=0;c<8;c++) p9[c] = b2f(pr[511 + 8*l + c]);
    u32 wv[8];
    #pragma unroll
    for (int b6=0;b6<2;b6++){
      float s6 = prefix * (b6 ? p6 : 1.f - p6);
      #pragma unroll
      for (int b7=0;b7<2;b7++){
        float q7 = p7[b6];
        float s7 = s6 * (b7 ? q7 : 1.f - q7);
        #pragma unroll
        for (int b8=0;b8<2;b8++){
          float q8 = p8[2*b6+b7];
          float s8 = s7 * (b8 ? q8 : 1.f - q8);
          float q9 = p9[4*b6+2*b7+b8];
          wv[4*b6+2*b7+b8] = (u32)f2b(s8 * (1.f - q9)) | ((u32)f2b(s8 * q9) << 16);
        }
      }
    }
    int s0 = ((2*l  ) ^ (r&7)) * 8;               // swizzled store: chunk ^ (row&7)
    int s1 = ((2*l+1) ^ (r&7)) * 8;
    *(uint4*)(pl + r*1024 + s0) = make_uint4(wv[0],wv[1],wv[2],wv[3]);
    *(uint4*)(pl + r*1024 + s1) = make_uint4(wv[4],wv[5],wv[6],wv[7]);
  }

  const int r15 = l & 15, q = l >> 4;
  f32x4 acc0 = {0.f,0.f,0.f,0.f}, acc1 = {0.f,0.f,0.f,0.f};
  const u16* bp0 = phiT + (size_t)r15*NP + q*8;
  const u16* bp1 = phiT + (size_t)(16+r15)*NP + q*8;
  #pragma unroll 4
  for (int kk=0; kk<32; ++kk){
    int slot = ((q + kk*4) ^ (r15 & 7)) * 8;
    short8 a  = *(const short8*)(pl + r15*1024 + slot);
    short8 b0 = *(const short8*)(bp0 + kk*32);
    short8 b1 = *(const short8*)(bp1 + kk*32);
    acc0 = __builtin_amdgcn_mfma_f32_16x16x32_bf16(a, b0, acc0, 0,0,0);
    acc1 = __builtin_amdgcn_mfma_f32_16x16x32_bf16(a, b1, acc1, 0,0,0);
  }
  #pragma unroll
  for (int r=0;r<4;r++){
    int row = row0 + q*4 + r;
    out[row*24 + r15] = acc0[r];
    if (r15 < 8) out[row*24 + 16 + r15] = acc1[r];
  }
}

extern "C" void kernel_launch(void* const* d_in, const int* in_sizes, int n_in,
                              void* d_out, int out_size, void* d_ws, size_t ws_size,
                              hipStream_t stream){
  const float* xs  = (const float*)d_in[0];
  const float* W   = (const float*)d_in[1];
  const float* b   = (const float*)d_in[2];
  const float* phi = (const float*)d_in[3];
  float* out = (float*)d_out;
  char* ws = (char*)d_ws;
  u16* Wb    = (u16*)(ws + 0);          //  4,194,304 B
  u16* probs = (u16*)(ws + 4194304);    // 16,777,216 B
  u16* phiT  = (u16*)(ws + 20971520);   //     65,536 B
  (void)in_sizes; (void)n_in; (void)out_size; (void)ws_size;

  hipFuncSetAttribute((const void*)k_gemm_sig, hipFuncAttributeMaxDynamicSharedMemorySize, 131072);
  hipFuncSetAttribute((const void*)k_ppout,    hipFuncAttributeMaxDynamicSharedMemorySize, 65536);

  k_prep   <<<1152, 256, 0, stream>>>(W, phi, Wb, phiT);
  k_gemm_sig<<<256, 512, 131072, stream>>>(xs, Wb, b, probs);
  k_ppout  <<<256, 128, 65536, stream>>>(probs, phiT, out);
}

// Round 10
// 74.284 us; speedup vs baseline: 1.1882x; 1.1882x over previous
//
#include <hip/hip_runtime.h>
#include <hip/hip_bf16.h>

typedef unsigned short u16;
typedef unsigned int u32;
typedef __attribute__((ext_vector_type(8))) short short8;
typedef __attribute__((ext_vector_type(4))) float f32x4;

#define KDIM 2048
#define NP 1024

__device__ __forceinline__ float b2f(u16 u){
  union{u32 i; float f;} v; v.i = ((u32)u)<<16; return v.f;
}
__device__ __forceinline__ u16 f2b(float f){
  u32 x = __float_as_uint(f);
  return (u16)((x + 0x7fffu + ((x>>16)&1u)) >> 16);
}

__device__ __forceinline__ void gload16(const u16* g, u16* l){
  __builtin_amdgcn_global_load_lds((const __attribute__((address_space(1))) u32*)g,
                                   (__attribute__((address_space(3))) u32*)l, 16, 0, 0);
}

// ---- K0: xs f32->bf16 + W f32->bf16 padded + phi->phiT, one launch ----
__global__ __launch_bounds__(256) void k_prep_all(const float* __restrict__ xs, const float* __restrict__ W,
                                                  const float* __restrict__ phi,
                                                  u16* __restrict__ A, u16* __restrict__ Wb,
                                                  u16* __restrict__ phiT){
  int bid = blockIdx.x;
  if (bid < 8192){                                  // xs: 8192x2048 f32 -> bf16
    int i = bid*256 + threadIdx.x;
    const float4* s = (const float4*)xs;
    float4 a = s[2*i], c = s[2*i+1];
    u32 o0 = (u32)f2b(a.x) | ((u32)f2b(a.y)<<16);
    u32 o1 = (u32)f2b(a.z) | ((u32)f2b(a.w)<<16);
    u32 o2 = (u32)f2b(c.x) | ((u32)f2b(c.y)<<16);
    u32 o3 = (u32)f2b(c.z) | ((u32)f2b(c.w)<<16);
    *(uint4*)(A + 8*i) = make_uint4(o0,o1,o2,o3);
  } else if (bid < 9216){                           // W: 1023x2048 -> 1024x2048 bf16
    int i = (bid-8192)*256 + threadIdx.x;
    int e = i*8; int row = e >> 11;
    u32 o0=0,o1=0,o2=0,o3=0;
    if (row < 1023){
      const float4* s = (const float4*)(W + e);
      float4 a = s[0], c = s[1];
      o0 = (u32)f2b(a.x) | ((u32)f2b(a.y)<<16);
      o1 = (u32)f2b(a.z) | ((u32)f2b(a.w)<<16);
      o2 = (u32)f2b(c.x) | ((u32)f2b(c.y)<<16);
      o3 = (u32)f2b(c.z) | ((u32)f2b(c.w)<<16);
    }
    *(uint4*)(Wb + e) = make_uint4(o0,o1,o2,o3);
  } else {                                          // phi: 1024x24 -> phiT 32x1024
    int i = (bid-9216)*256 + threadIdx.x;
    int d = i >> 10, leaf = i & 1023;
    float v = (d < 24) ? phi[leaf*24 + d] : 0.f;
    phiT[i] = f2b(v);
  }
}

// ---- K1: probs = sigmoid(A @ Wb^T + b) -- R2-EXACT (measured 39.1us) ----
// BM=256 BN=128 BK=64, 512 thr (8 waves, 4M x 2N, 64x64/wave), dbuf LDS 96KB,
// XOR-swizzled tiles (chunk ^= row&7), counted vmcnt(3), raw barriers, setprio.
__global__ __launch_bounds__(512, 2) void k_gemm_sig(const u16* __restrict__ A, const u16* __restrict__ Wb,
                                                     const float* __restrict__ b, u16* __restrict__ probs){
  extern __shared__ u16 smem[];
  const int t = threadIdx.x;
  const int l = t & 63;
  const int w = t >> 6;
  const int wm = w >> 1, wn = w & 1;
  const int bid = (int)blockIdx.x;
  const int wg = (bid & 7) * 32 + (bid >> 3);          // XCD-chunked, bijective (256%8==0)
  const int rowB = (wg >> 3) * 256;
  const int colB = (wg & 7) * 128;

  // staging: linear LDS dest (wave base + lane*16), inverse-swizzled global src
  const int locA0 = w*128 + l;
  const int locA1 = locA0 + 64;
  const int rA0 = locA0 >> 3, cA0 = (locA0 & 7) ^ (rA0 & 7);
  const int rA1 = locA1 >> 3, cA1 = (locA1 & 7) ^ (rA1 & 7);
  const int locB = w*64 + l;
  const int rB = locB >> 3, cB = (locB & 7) ^ (rB & 7);
  const u16* gA0 = A  + (size_t)(rowB + rA0) * KDIM + cA0 * 8;
  const u16* gA1 = A  + (size_t)(rowB + rA1) * KDIM + cA1 * 8;
  const u16* gB  = Wb + (size_t)(colB + rB ) * KDIM + cB  * 8;
  const int dA0 = locA0 * 8, dA1 = locA1 * 8, dB = locB * 8;

  // fragment reads: slot s = (ks*4 + q) ^ (l&7); row&7 == l&7 for all frag rows
  const int r15 = l & 15, q = l >> 4, b7 = l & 7;
  const int xo0 = ((q    ) ^ b7) * 8;
  const int xo1 = ((4 + q) ^ b7) * 8;
  const int aRow = (wm*64 + r15) * 64;
  const int bRow = (wn*64 + r15) * 64;

  f32x4 acc[4][4] = {};

#define AB(buf) (smem + (buf)*24576)
#define BB(buf) (smem + (buf)*24576 + 16384)
#define STAGE(p, buf, ko) do{ \
    gload16(gA0 + (size_t)(p)*128*KDIM + (ko), AB(buf) + (p)*8192 + dA0); \
    gload16(gA1 + (size_t)(p)*128*KDIM + (ko), AB(buf) + (p)*8192 + dA1); \
    gload16(gB  + (size_t)(p)*64 *KDIM + (ko), BB(buf) + (p)*4096 + dB ); \
  }while(0)

  STAGE(0, 0, 0); STAGE(1, 0, 0);                       // prologue: tile 0 fully issued

  for (int tk = 0; tk < 31; ++tk){
    const int cur = tk & 1, nxt = cur ^ 1;
    const int ko = (tk + 1) * 64;
    const u16* Ab = AB(cur); const u16* Bb = BB(cur);
    STAGE(0, nxt, ko);                                  // 3 loads of t+1 in flight
    asm volatile("s_waitcnt vmcnt(3)" ::: "memory");    // tile t fully landed
    __builtin_amdgcn_s_barrier();
    asm volatile("" ::: "memory");
    short8 af[4], bf[4];
    #pragma unroll
    for (int m=0;m<4;m++) af[m] = *(const short8*)(Ab + aRow + m*1024 + xo0);
    #pragma unroll
    for (int n=0;n<4;n++) bf[n] = *(const short8*)(Bb + bRow + n*1024 + xo0);
    __builtin_amdgcn_s_setprio(1);
    #pragma unroll
    for (int m=0;m<4;m++){
      #pragma unroll
      for (int n=0;n<4;n++) acc[m][n] = __builtin_amdgcn_mfma_f32_16x16x32_bf16(af[m], bf[n], acc[m][n], 0,0,0);
    }
    __builtin_amdgcn_s_setprio(0);
    STAGE(1, nxt, ko);
    #pragma unroll
    for (int m=0;m<4;m++) af[m] = *(const short8*)(Ab + aRow + m*1024 + xo1);
    #pragma unroll
    for (int n=0;n<4;n++) bf[n] = *(const short8*)(Bb + bRow + n*1024 + xo1);
    __builtin_amdgcn_s_setprio(1);
    #pragma unroll
    for (int m=0;m<4;m++){
      #pragma unroll
      for (int n=0;n<4;n++) acc[m][n] = __builtin_amdgcn_mfma_f32_16x16x32_bf16(af[m], bf[n], acc[m][n], 0,0,0);
    }
    __builtin_amdgcn_s_setprio(0);
    __builtin_amdgcn_s_barrier();                       // reads of cur consumed; nxt-writes safe
    asm volatile("" ::: "memory");
  }
  {                                                     // tail tile 31 (cur=1), no prefetch
    const u16* Ab = AB(1); const u16* Bb = BB(1);
    asm volatile("s_waitcnt vmcnt(0)" ::: "memory");
    __builtin_amdgcn_s_barrier();
    asm volatile("" ::: "memory");
    short8 af[4], bf[4];
    #pragma unroll
    for (int m=0;m<4;m++) af[m] = *(const short8*)(Ab + aRow + m*1024 + xo0);
    #pragma unroll
    for (int n=0;n<4;n++) bf[n] = *(const short8*)(Bb + bRow + n*1024 + xo0);
    #pragma unroll
    for (int m=0;m<4;m++){
      #pragma unroll
      for (int n=0;n<4;n++) acc[m][n] = __builtin_amdgcn_mfma_f32_16x16x32_bf16(af[m], bf[n], acc[m][n], 0,0,0);
    }
    #pragma unroll
    for (int m=0;m<4;m++) af[m] = *(const short8*)(Ab + aRow + m*1024 + xo1);
    #pragma unroll
    for (int n=0;n<4;n++) bf[n] = *(const short8*)(Bb + bRow + n*1024 + xo1);
    #pragma unroll
    for (int m=0;m<4;m++){
      #pragma unroll
      for (int n=0;n<4;n++) acc[m][n] = __builtin_amdgcn_mfma_f32_16x16x32_bf16(af[m], bf[n], acc[m][n], 0,0,0);
    }
  }
#undef STAGE
#undef AB
#undef BB

  #pragma unroll
  for (int n=0;n<4;n++){
    int col = colB + wn*64 + n*16 + r15;
    float bb = (col < 1023) ? b[col] : 0.f;
    #pragma unroll
    for (int m=0;m<4;m++){
      #pragma unroll
      for (int r=0;r<4;r++){
        int row = rowB + wm*64 + m*16 + q*4 + r;        // measured C/D layout
        float x = acc[m][n][r] + bb;
        float p = 1.f / (1.f + __expf(-x));
        probs[(size_t)row*NP + col] = f2b(p);
      }
    }
  }
}

// ---- K2: fused leaf products + pp@phi (R7/R8-proven: 128 thr, 2 waves,
// 64KB LDS = 2 x 16rows x 1024 u16, 256 blocks) ----
__global__ __launch_bounds__(128) void k_ppout(const u16* __restrict__ probs, const u16* __restrict__ phiT,
                                               float* __restrict__ out){
  extern __shared__ u16 ppL[];                      // 2 waves * 16384 u16 = 65,536 B
  const int t = threadIdx.x;
  const int l = t & 63;
  const int w = t >> 6;
  u16* pl = ppL + w*16384;
  const int row0 = blockIdx.x*32 + w*16;

  for (int r=0; r<16; ++r){
    const u16* pr = probs + (size_t)(row0 + r)*NP;
    float prefix = 1.f;
    #pragma unroll
    for (int k=0;k<6;k++){
      int i = l >> (6-k);
      int bit = (l >> (5-k)) & 1;
      float p = b2f(pr[(1<<k)-1 + i]);
      prefix *= bit ? p : (1.f - p);
    }
    float p6 = b2f(pr[63 + l]);
    float p7[2], p8[4], p9[8];
    #pragma unroll
    for (int c=0;c<2;c++) p7[c] = b2f(pr[127 + 2*l + c]);
    #pragma unroll
    for (int c=0;c<4;c++) p8[c] = b2f(pr[255 + 4*l + c]);
    #pragma unroll
    for (int c=0;c<8;c++) p9[c] = b2f(pr[511 + 8*l + c]);
    u32 wv[8];
    #pragma unroll
    for (int b6=0;b6<2;b6++){
      float s6 = prefix * (b6 ? p6 : 1.f - p6);
      #pragma unroll
      for (int b7=0;b7<2;b7++){
        float q7 = p7[b6];
        float s7 = s6 * (b7 ? q7 : 1.f - q7);
        #pragma unroll
        for (int b8=0;b8<2;b8++){
          float q8 = p8[2*b6+b7];
          float s8 = s7 * (b8 ? q8 : 1.f - q8);
          float q9 = p9[4*b6+2*b7+b8];
          wv[4*b6+2*b7+b8] = (u32)f2b(s8 * (1.f - q9)) | ((u32)f2b(s8 * q9) << 16);
        }
      }
    }
    int s0 = ((2*l  ) ^ (r&7)) * 8;                 // swizzled store: chunk ^ (row&7)
    int s1 = ((2*l+1) ^ (r&7)) * 8;
    *(uint4*)(pl + r*1024 + s0) = make_uint4(wv[0],wv[1],wv[2],wv[3]);
    *(uint4*)(pl + r*1024 + s1) = make_uint4(wv[4],wv[5],wv[6],wv[7]);
  }

  const int r15 = l & 15, q = l >> 4;
  f32x4 acc0 = {0.f,0.f,0.f,0.f}, acc1 = {0.f,0.f,0.f,0.f};
  const u16* bp0 = phiT + (size_t)r15*NP + q*8;
  const u16* bp1 = phiT + (size_t)(16+r15)*NP + q*8;
  #pragma unroll 4
  for (int kk=0; kk<32; ++kk){
    int slot = ((q + kk*4) ^ (r15 & 7)) * 8;
    short8 a  = *(const short8*)(pl + r15*1024 + slot);
    short8 b0 = *(const short8*)(bp0 + kk*32);
    short8 b1 = *(const short8*)(bp1 + kk*32);
    acc0 = __builtin_amdgcn_mfma_f32_16x16x32_bf16(a, b0, acc0, 0,0,0);
    acc1 = __builtin_amdgcn_mfma_f32_16x16x32_bf16(a, b1, acc1, 0,0,0);
  }
  #pragma unroll
  for (int r=0;r<4;r++){
    int row = row0 + q*4 + r;
    out[row*24 + r15] = acc0[r];
    if (r15 < 8) out[row*24 + 16 + r15] = acc1[r];
  }
}

extern "C" void kernel_launch(void* const* d_in, const int* in_sizes, int n_in,
                              void* d_out, int out_size, void* d_ws, size_t ws_size,
                              hipStream_t stream){
  const float* xs  = (const float*)d_in[0];
  const float* W   = (const float*)d_in[1];
  const float* b   = (const float*)d_in[2];
  const float* phi = (const float*)d_in[3];
  float* out = (float*)d_out;
  char* ws = (char*)d_ws;
  u16* Wb    = (u16*)(ws + 0);          //  4,194,304 B
  u16* probs = (u16*)(ws + 4194304);    // 16,777,216 B
  u16* phiT  = (u16*)(ws + 20971520);   //     65,536 B
  u16* A     = (u16*)(ws + 21037056);   // 33,554,432 B
  (void)in_sizes; (void)n_in; (void)out_size; (void)ws_size;

  hipFuncSetAttribute((const void*)k_gemm_sig, hipFuncAttributeMaxDynamicSharedMemorySize, 98304);
  hipFuncSetAttribute((const void*)k_ppout,    hipFuncAttributeMaxDynamicSharedMemorySize, 65536);

  k_prep_all<<<9344, 256, 0, stream>>>(xs, W, phi, A, Wb, phiT);
  k_gemm_sig<<<256, 512, 98304, stream>>>(A, Wb, b, probs);
  k_ppout   <<<256, 128, 65536, stream>>>(probs, phiT, out);
}

// Round 11
// 65.664 us; speedup vs baseline: 1.3442x; 1.1313x over previous
//
#include <hip/hip_runtime.h>
#include <hip/hip_bf16.h>

typedef unsigned short u16;
typedef unsigned int u32;
typedef __attribute__((ext_vector_type(8))) short short8;
typedef __attribute__((ext_vector_type(4))) float f32x4;

#define KDIM 2048
#define NP 1024

__device__ __forceinline__ float b2f(u16 u){
  union{u32 i; float f;} v; v.i = ((u32)u)<<16; return v.f;
}
__device__ __forceinline__ u16 f2b(float f){
  u32 x = __float_as_uint(f);
  return (u16)((x + 0x7fffu + ((x>>16)&1u)) >> 16);
}

__device__ __forceinline__ void gload16(const u16* g, u16* l){
  __builtin_amdgcn_global_load_lds((const __attribute__((address_space(1))) u32*)g,
                                   (__attribute__((address_space(3))) u32*)l, 16, 0, 0);
}

// ---- K0: xs f32->bf16 + W f32->bf16 padded + phi->phiT, one launch ----
__global__ __launch_bounds__(256) void k_prep_all(const float* __restrict__ xs, const float* __restrict__ W,
                                                  const float* __restrict__ phi,
                                                  u16* __restrict__ A, u16* __restrict__ Wb,
                                                  u16* __restrict__ phiT){
  int bid = blockIdx.x;
  if (bid < 8192){                                  // xs: 8192x2048 f32 -> bf16
    int i = bid*256 + threadIdx.x;
    const float4* s = (const float4*)xs;
    float4 a = s[2*i], c = s[2*i+1];
    u32 o0 = (u32)f2b(a.x) | ((u32)f2b(a.y)<<16);
    u32 o1 = (u32)f2b(a.z) | ((u32)f2b(a.w)<<16);
    u32 o2 = (u32)f2b(c.x) | ((u32)f2b(c.y)<<16);
    u32 o3 = (u32)f2b(c.z) | ((u32)f2b(c.w)<<16);
    *(uint4*)(A + 8*i) = make_uint4(o0,o1,o2,o3);
  } else if (bid < 9216){                           // W: 1023x2048 -> 1024x2048 bf16
    int i = (bid-8192)*256 + threadIdx.x;
    int e = i*8; int row = e >> 11;
    u32 o0=0,o1=0,o2=0,o3=0;
    if (row < 1023){
      const float4* s = (const float4*)(W + e);
      float4 a = s[0], c = s[1];
      o0 = (u32)f2b(a.x) | ((u32)f2b(a.y)<<16);
      o1 = (u32)f2b(a.z) | ((u32)f2b(a.w)<<16);
      o2 = (u32)f2b(c.x) | ((u32)f2b(c.y)<<16);
      o3 = (u32)f2b(c.z) | ((u32)f2b(c.w)<<16);
    }
    *(uint4*)(Wb + e) = make_uint4(o0,o1,o2,o3);
  } else {                                          // phi: 1024x24 -> phiT 32x1024
    int i = (bid-9216)*256 + threadIdx.x;
    int d = i >> 10, leaf = i & 1023;
    float v = (d < 24) ? phi[leaf*24 + d] : 0.f;
    phiT[i] = f2b(v);
  }
}

// ---- K1: probs = sigmoid(A @ Wb^T + b) -- R2-EXACT (measured 39.1us) ----
// BM=256 BN=128 BK=64, 512 thr (8 waves, 4M x 2N, 64x64/wave), dbuf LDS 96KB,
// XOR-swizzled tiles (chunk ^= row&7), counted vmcnt(3), raw barriers, setprio.
__global__ __launch_bounds__(512, 2) void k_gemm_sig(const u16* __restrict__ A, const u16* __restrict__ Wb,
                                                     const float* __restrict__ b, u16* __restrict__ probs){
  extern __shared__ u16 smem[];
  const int t = threadIdx.x;
  const int l = t & 63;
  const int w = t >> 6;
  const int wm = w >> 1, wn = w & 1;
  const int bid = (int)blockIdx.x;
  const int wg = (bid & 7) * 32 + (bid >> 3);          // XCD-chunked, bijective (256%8==0)
  const int rowB = (wg >> 3) * 256;
  const int colB = (wg & 7) * 128;

  // staging: linear LDS dest (wave base + lane*16), inverse-swizzled global src
  const int locA0 = w*128 + l;
  const int locA1 = locA0 + 64;
  const int rA0 = locA0 >> 3, cA0 = (locA0 & 7) ^ (rA0 & 7);
  const int rA1 = locA1 >> 3, cA1 = (locA1 & 7) ^ (rA1 & 7);
  const int locB = w*64 + l;
  const int rB = locB >> 3, cB = (locB & 7) ^ (rB & 7);
  const u16* gA0 = A  + (size_t)(rowB + rA0) * KDIM + cA0 * 8;
  const u16* gA1 = A  + (size_t)(rowB + rA1) * KDIM + cA1 * 8;
  const u16* gB  = Wb + (size_t)(colB + rB ) * KDIM + cB  * 8;
  const int dA0 = locA0 * 8, dA1 = locA1 * 8, dB = locB * 8;

  // fragment reads: slot s = (ks*4 + q) ^ (l&7); row&7 == l&7 for all frag rows
  const int r15 = l & 15, q = l >> 4, b7 = l & 7;
  const int xo0 = ((q    ) ^ b7) * 8;
  const int xo1 = ((4 + q) ^ b7) * 8;
  const int aRow = (wm*64 + r15) * 64;
  const int bRow = (wn*64 + r15) * 64;

  f32x4 acc[4][4] = {};

#define AB(buf) (smem + (buf)*24576)
#define BB(buf) (smem + (buf)*24576 + 16384)
#define STAGE(p, buf, ko) do{ \
    gload16(gA0 + (size_t)(p)*128*KDIM + (ko), AB(buf) + (p)*8192 + dA0); \
    gload16(gA1 + (size_t)(p)*128*KDIM + (ko), AB(buf) + (p)*8192 + dA1); \
    gload16(gB  + (size_t)(p)*64 *KDIM + (ko), BB(buf) + (p)*4096 + dB ); \
  }while(0)

  STAGE(0, 0, 0); STAGE(1, 0, 0);                       // prologue: tile 0 fully issued

  for (int tk = 0; tk < 31; ++tk){
    const int cur = tk & 1, nxt = cur ^ 1;
    const int ko = (tk + 1) * 64;
    const u16* Ab = AB(cur); const u16* Bb = BB(cur);
    STAGE(0, nxt, ko);                                  // 3 loads of t+1 in flight
    asm volatile("s_waitcnt vmcnt(3)" ::: "memory");    // tile t fully landed
    __builtin_amdgcn_s_barrier();
    asm volatile("" ::: "memory");
    short8 af[4], bf[4];
    #pragma unroll
    for (int m=0;m<4;m++) af[m] = *(const short8*)(Ab + aRow + m*1024 + xo0);
    #pragma unroll
    for (int n=0;n<4;n++) bf[n] = *(const short8*)(Bb + bRow + n*1024 + xo0);
    __builtin_amdgcn_s_setprio(1);
    #pragma unroll
    for (int m=0;m<4;m++){
      #pragma unroll
      for (int n=0;n<4;n++) acc[m][n] = __builtin_amdgcn_mfma_f32_16x16x32_bf16(af[m], bf[n], acc[m][n], 0,0,0);
    }
    __builtin_amdgcn_s_setprio(0);
    STAGE(1, nxt, ko);
    #pragma unroll
    for (int m=0;m<4;m++) af[m] = *(const short8*)(Ab + aRow + m*1024 + xo1);
    #pragma unroll
    for (int n=0;n<4;n++) bf[n] = *(const short8*)(Bb + bRow + n*1024 + xo1);
    __builtin_amdgcn_s_setprio(1);
    #pragma unroll
    for (int m=0;m<4;m++){
      #pragma unroll
      for (int n=0;n<4;n++) acc[m][n] = __builtin_amdgcn_mfma_f32_16x16x32_bf16(af[m], bf[n], acc[m][n], 0,0,0);
    }
    __builtin_amdgcn_s_setprio(0);
    __builtin_amdgcn_s_barrier();                       // reads of cur consumed; nxt-writes safe
    asm volatile("" ::: "memory");
  }
  {                                                     // tail tile 31 (cur=1), no prefetch
    const u16* Ab = AB(1); const u16* Bb = BB(1);
    asm volatile("s_waitcnt vmcnt(0)" ::: "memory");
    __builtin_amdgcn_s_barrier();
    asm volatile("" ::: "memory");
    short8 af[4], bf[4];
    #pragma unroll
    for (int m=0;m<4;m++) af[m] = *(const short8*)(Ab + aRow + m*1024 + xo0);
    #pragma unroll
    for (int n=0;n<4;n++) bf[n] = *(const short8*)(Bb + bRow + n*1024 + xo0);
    #pragma unroll
    for (int m=0;m<4;m++){
      #pragma unroll
      for (int n=0;n<4;n++) acc[m][n] = __builtin_amdgcn_mfma_f32_16x16x32_bf16(af[m], bf[n], acc[m][n], 0,0,0);
    }
    #pragma unroll
    for (int m=0;m<4;m++) af[m] = *(const short8*)(Ab + aRow + m*1024 + xo1);
    #pragma unroll
    for (int n=0;n<4;n++) bf[n] = *(const short8*)(Bb + bRow + n*1024 + xo1);
    #pragma unroll
    for (int m=0;m<4;m++){
      #pragma unroll
      for (int n=0;n<4;n++) acc[m][n] = __builtin_amdgcn_mfma_f32_16x16x32_bf16(af[m], bf[n], acc[m][n], 0,0,0);
    }
  }
#undef STAGE
#undef AB
#undef BB

  #pragma unroll
  for (int n=0;n<4;n++){
    int col = colB + wn*64 + n*16 + r15;
    float bb = (col < 1023) ? b[col] : 0.f;
    #pragma unroll
    for (int m=0;m<4;m++){
      #pragma unroll
      for (int r=0;r<4;r++){
        int row = rowB + wm*64 + m*16 + q*4 + r;        // measured C/D layout
        float x = acc[m][n][r] + bb;
        float p = 1.f / (1.f + __expf(-x));
        probs[(size_t)row*NP + col] = f2b(p);
      }
    }
  }
}

// ---- K2: fused leaf products + pp@phi. Restructured for occupancy:
// 256 thr (4 waves) share ONE 16-row tile (32KB LDS, 5 blocks/CU = 20 waves/CU).
// Wave w computes tree for rows 4w..4w+3 (4 serial rows, was 16); after barrier
// wave 0 does the MFMA for d0-15, wave 1 for d16-23. Per-row code unchanged. ----
__global__ __launch_bounds__(256) void k_ppout(const u16* __restrict__ probs, const u16* __restrict__ phiT,
                                               float* __restrict__ out){
  extern __shared__ u16 ppL[];                      // 16 rows * 1024 u16 = 32,768 B
  const int t = threadIdx.x;
  const int l = t & 63;
  const int w = t >> 6;
  const int row0 = blockIdx.x*16;

  for (int rr=0; rr<4; ++rr){
    const int r = w*4 + rr;                         // local row 0..15
    const u16* pr = probs + (size_t)(row0 + r)*NP;
    float prefix = 1.f;
    #pragma unroll
    for (int k=0;k<6;k++){
      int i = l >> (6-k);
      int bit = (l >> (5-k)) & 1;
      float p = b2f(pr[(1<<k)-1 + i]);
      prefix *= bit ? p : (1.f - p);
    }
    float p6 = b2f(pr[63 + l]);
    float p7[2], p8[4], p9[8];
    #pragma unroll
    for (int c=0;c<2;c++) p7[c] = b2f(pr[127 + 2*l + c]);
    #pragma unroll
    for (int c=0;c<4;c++) p8[c] = b2f(pr[255 + 4*l + c]);
    #pragma unroll
    for (int c=0;c<8;c++) p9[c] = b2f(pr[511 + 8*l + c]);
    u32 wv[8];
    #pragma unroll
    for (int b6=0;b6<2;b6++){
      float s6 = prefix * (b6 ? p6 : 1.f - p6);
      #pragma unroll
      for (int b7=0;b7<2;b7++){
        float q7 = p7[b6];
        float s7 = s6 * (b7 ? q7 : 1.f - q7);
        #pragma unroll
        for (int b8=0;b8<2;b8++){
          float q8 = p8[2*b6+b7];
          float s8 = s7 * (b8 ? q8 : 1.f - q8);
          float q9 = p9[4*b6+2*b7+b8];
          wv[4*b6+2*b7+b8] = (u32)f2b(s8 * (1.f - q9)) | ((u32)f2b(s8 * q9) << 16);
        }
      }
    }
    int s0 = ((2*l  ) ^ (r&7)) * 8;                 // swizzled store: chunk ^ (row&7)
    int s1 = ((2*l+1) ^ (r&7)) * 8;
    *(uint4*)(ppL + r*1024 + s0) = make_uint4(wv[0],wv[1],wv[2],wv[3]);
    *(uint4*)(ppL + r*1024 + s1) = make_uint4(wv[4],wv[5],wv[6],wv[7]);
  }
  __syncthreads();
  if (w >= 2) return;                               // waves 2,3 done (tree only)

  const int r15 = l & 15, q = l >> 4;
  f32x4 acc = {0.f,0.f,0.f,0.f};
  const u16* bp = phiT + (size_t)(w*16 + r15)*NP + q*8;   // wave0: d0-15, wave1: d16-31
  #pragma unroll 4
  for (int kk=0; kk<32; ++kk){
    int slot = ((q + kk*4) ^ (r15 & 7)) * 8;
    short8 a  = *(const short8*)(ppL + r15*1024 + slot);
    short8 b0 = *(const short8*)(bp + kk*32);
    acc = __builtin_amdgcn_mfma_f32_16x16x32_bf16(a, b0, acc, 0,0,0);
  }
  #pragma unroll
  for (int r=0;r<4;r++){
    int row = row0 + q*4 + r;
    if (w == 0)           out[row*24 + r15]      = acc[r];
    else if (r15 < 8)     out[row*24 + 16 + r15] = acc[r];
  }
}

extern "C" void kernel_launch(void* const* d_in, const int* in_sizes, int n_in,
                              void* d_out, int out_size, void* d_ws, size_t ws_size,
                              hipStream_t stream){
  const float* xs  = (const float*)d_in[0];
  const float* W   = (const float*)d_in[1];
  const float* b   = (const float*)d_in[2];
  const float* phi = (const float*)d_in[3];
  float* out = (float*)d_out;
  char* ws = (char*)d_ws;
  u16* Wb    = (u16*)(ws + 0);          //  4,194,304 B
  u16* probs = (u16*)(ws + 4194304);    // 16,777,216 B
  u16* phiT  = (u16*)(ws + 20971520);   //     65,536 B
  u16* A     = (u16*)(ws + 21037056);   // 33,554,432 B
  (void)in_sizes; (void)n_in; (void)out_size; (void)ws_size;

  hipFuncSetAttribute((const void*)k_gemm_sig, hipFuncAttributeMaxDynamicSharedMemorySize, 98304);
  hipFuncSetAttribute((const void*)k_ppout,    hipFuncAttributeMaxDynamicSharedMemorySize, 32768);

  k_prep_all<<<9344, 256, 0, stream>>>(xs, W, phi, A, Wb, phiT);
  k_gemm_sig<<<256, 512, 98304, stream>>>(A, Wb, b, probs);
  k_ppout   <<<512, 256, 32768, stream>>>(probs, phiT, out);
}